// Round 4
// baseline (372.137 us; speedup 1.0000x reference)
//
#include <hip/hip_runtime.h>
#include <hip/hip_bf16.h>
#include <cstdint>
#include <cstddef>

// B=4, S=2048, D=1024, H=16, DH=64.  BS = 8192 rows.
// pack_all: x->bf16; Wqkv -> [3072 n][1024 k] bf16; bias pack; Wo -> [1024][1024]
// gemm_qkv: QKV[8192][3072] bf16 (Q cols pre-scaled by 0.125*log2(e), bias folded)
// vt: V part of QKV -> Vtg[bh=64][e=64][s=2048] bf16 (global transpose)
// attn: flash, S^T trick, exp2 domain -> MH [8192][1024] bf16
// gemm_out: out[8192][1024] f32 = MH @ Wo^T + bo

typedef unsigned short u16;
typedef unsigned int u32;
typedef __attribute__((ext_vector_type(8))) __bf16 bf16x8;
typedef __attribute__((ext_vector_type(8))) unsigned short u16x8;
typedef __attribute__((ext_vector_type(4))) float f32x4;
typedef __attribute__((ext_vector_type(4))) unsigned int u32x4;

__device__ __forceinline__ u16 f2bf(float f) {
  union { __hip_bfloat16 h; u16 u; } c;
  c.h = __float2bfloat16(f);
  return c.u;
}
__device__ __forceinline__ u32 pk2(float a, float b) {
  return (u32)f2bf(a) | ((u32)f2bf(b) << 16);
}
// exp2 via the amdgcn builtin (v_exp_f32). NOTE: __exp2f collides with a
// glibc math.h macro in this env — do not use it.
__device__ __forceinline__ float ex2(float x) {
  return __builtin_amdgcn_exp2f(x);
}

// async 16B global->LDS; LDS dest is wave-uniform base + lane*16.
__device__ __forceinline__ void async16(const void* g, void* l) {
  __builtin_amdgcn_global_load_lds(
      (const __attribute__((address_space(1))) void*)g,
      (__attribute__((address_space(3))) void*)l, 16, 0, 0);
}

// --------------------------------------------------------- merged packs ----
// grid: [0,8192) x->bf16 | [8192,11264) Wqkv | [11264,11276) bias | rest Wo
__global__ void k_pack_all(const float* __restrict__ x,
                           const float* __restrict__ Wq, const float* __restrict__ Wk,
                           const float* __restrict__ Wv,
                           const float* __restrict__ bq, const float* __restrict__ bk,
                           const float* __restrict__ bv,
                           const float* __restrict__ Wo,
                           u16* __restrict__ xb, u16* __restrict__ Wt,
                           float* __restrict__ bqkv, u16* __restrict__ Wot) {
  const int bid = blockIdx.x;
  if (bid < 8192) {
    const int i = (bid * 256 + threadIdx.x) * 4;
    const float4 v = *(const float4*)(x + i);
    ushort4 o;
    o.x = f2bf(v.x); o.y = f2bf(v.y); o.z = f2bf(v.z); o.w = f2bf(v.w);
    *(ushort4*)(xb + i) = o;
  } else if (bid < 11264) {
    const int gid = (bid - 8192) * 256 + threadIdx.x;
    const int n = gid >> 8;
    const int d0 = (gid & 255) << 2;
    const int proj = n >> 10, rem = n & 1023, h = rem >> 6, e = rem & 63;
    const float* Wp = (proj == 0) ? Wq : ((proj == 1) ? Wk : Wv);
    const float* src = Wp + h * 65536 + e;
    ushort4 o;
    o.x = f2bf(src[(d0 + 0) * 64]);
    o.y = f2bf(src[(d0 + 1) * 64]);
    o.z = f2bf(src[(d0 + 2) * 64]);
    o.w = f2bf(src[(d0 + 3) * 64]);
    *(ushort4*)(Wt + (size_t)n * 1024 + d0) = o;
  } else if (bid < 11276) {
    const int n = (bid - 11264) * 256 + threadIdx.x;
    const int proj = n >> 10, rem = n & 1023, h = rem >> 6, e = rem & 63;
    const float* bp = (proj == 0) ? bq : ((proj == 1) ? bk : bv);
    bqkv[n] = bp[h * 64 + e];
  } else {
    const int gid = (bid - 11276) * 256 + threadIdx.x;
    const int n = gid >> 8;
    const int d0 = (gid & 255) << 2;
    ushort4 o;
    o.x = f2bf(Wo[(size_t)(d0 + 0) * 1024 + n]);
    o.y = f2bf(Wo[(size_t)(d0 + 1) * 1024 + n]);
    o.z = f2bf(Wo[(size_t)(d0 + 2) * 1024 + n]);
    o.w = f2bf(Wo[(size_t)(d0 + 3) * 1024 + n]);
    *(ushort4*)(Wot + (size_t)n * 1024 + d0) = o;
  }
}

// ----------------------------------------------------------------- GEMM ----
// (m97 structure). MODE 0: bf16 out, Q cols scaled by 0.125*log2e (exp2 domain).
template <int MODE>
__global__ __launch_bounds__(256)
void k_gemm(const u16* __restrict__ A, const u16* __restrict__ Bt,
            const float* __restrict__ bias, void* __restrict__ Cout, int ldc) {
  __shared__ __align__(16) u16 Alds[128 * 32];
  __shared__ __align__(16) u16 Blds[128 * 32];
  const int t = threadIdx.x;
  const int lane = t & 63;
  const int w = t >> 6;
  const int l15 = lane & 15;
  const int quad = lane >> 4;
  const int wm = w >> 1, wn = w & 1;
  const int m0 = blockIdx.y << 7;
  const int n0 = blockIdx.x << 7;

  const u16* ga0 = A + (size_t)(m0 + (t >> 2)) * 1024 + (t & 3) * 8;
  const u16* ga1 = ga0 + (size_t)64 * 1024;
  const u16* gb0 = Bt + (size_t)(n0 + (t >> 2)) * 1024 + (t & 3) * 8;
  const u16* gb1 = gb0 + (size_t)64 * 1024;
  u16* const lA0 = Alds + w * 512;
  u16* const lA1 = Alds + w * 512 + 2048;
  u16* const lB0 = Blds + w * 512;
  u16* const lB1 = Blds + w * 512 + 2048;

  f32x4 acc[4][4];
#pragma unroll
  for (int mi = 0; mi < 4; ++mi)
#pragma unroll
    for (int ni = 0; ni < 4; ++ni) acc[mi][ni] = (f32x4){0.f, 0.f, 0.f, 0.f};

  for (int k0 = 0; k0 < 1024; k0 += 32) {
    __syncthreads();
    async16(ga0, lA0); async16(ga1, lA1);
    async16(gb0, lB0); async16(gb1, lB1);
    ga0 += 32; ga1 += 32; gb0 += 32; gb1 += 32;
    __syncthreads();
    bf16x8 af[4], bfr[4];
#pragma unroll
    for (int i = 0; i < 4; ++i) {
      af[i]  = *(const bf16x8*)(Alds + (wm * 64 + i * 16 + l15) * 32 + quad * 8);
      bfr[i] = *(const bf16x8*)(Blds + (wn * 64 + i * 16 + l15) * 32 + quad * 8);
    }
#pragma unroll
    for (int mi = 0; mi < 4; ++mi)
#pragma unroll
      for (int ni = 0; ni < 4; ++ni)
        acc[mi][ni] = __builtin_amdgcn_mfma_f32_16x16x32_bf16(af[mi], bfr[ni], acc[mi][ni], 0, 0, 0);
  }

  const int row0 = m0 + wm * 64;
  const int col0 = n0 + wn * 64;
  // Q prescale: 1/sqrt(64) * log2(e) so attention can use bare v_exp_f32 (exp2)
  const float qscale = (MODE == 0 && col0 < 1024) ? 0.125f * 1.4426950408889634f : 1.0f;
#pragma unroll
  for (int mi = 0; mi < 4; ++mi) {
#pragma unroll
    for (int ni = 0; ni < 4; ++ni) {
      const int col = col0 + ni * 16 + l15;
      const float bb = bias[col];
#pragma unroll
      for (int r = 0; r < 4; ++r) {
        const int row = row0 + mi * 16 + quad * 4 + r;
        const float v = (acc[mi][ni][r] + bb) * qscale;
        if (MODE == 0) ((u16*)Cout)[(size_t)row * ldc + col] = f2bf(v);
        else           ((float*)Cout)[(size_t)row * ldc + col] = v;
      }
    }
  }
}

// ------------------------------------------------- V global transpose ----
// Vtg[bh][e][s] = QKV[b*2048+s][2048 + h*64 + e]
__global__ __launch_bounds__(256)
void k_vt(const u16* __restrict__ qkv, u16* __restrict__ vtg) {
  __shared__ u16 tile[64][72];
  const int t = threadIdx.x;
  const int bh = blockIdx.y, b = bh >> 4, h = bh & 15;
  const int s0 = blockIdx.x << 6;
  {
    const int row = t >> 2, col0 = (t & 3) * 16;
    const u16* src = qkv + (size_t)(b * 2048 + s0 + row) * 3072 + 2048 + h * 64 + col0;
    const u16x8 v0 = *(const u16x8*)src;
    const u16x8 v1 = *(const u16x8*)(src + 8);
    *(u16x8*)&tile[row][col0] = v0;
    *(u16x8*)&tile[row][col0 + 8] = v1;
  }
  __syncthreads();
  {
    const int e = t >> 2, sc = (t & 3) * 16;
    u16 buf[16];
#pragma unroll
    for (int i = 0; i < 16; ++i) buf[i] = tile[sc + i][e];
    u16* dst = vtg + ((size_t)bh * 64 + e) * 2048 + s0 + sc;
    *(u16x8*)dst = *(const u16x8*)&buf[0];
    *(u16x8*)(dst + 8) = *(const u16x8*)&buf[8];
  }
}

// ------------------------------------------------------------- attention ----
// Block = (bh, 256 q rows), 4 waves x 64 q each (4 groups of 16).
// Per K-tile (128 keys): S^T = K.Q^T (A = K-frags from LDS under the
// permutation pi; B = Q-frags held in regs). Scores already in log2-domain
// (gemm prescale) -> p = exp2(s). Packed exp2 register pairs ARE the PV
// A-fragment for key-chunk ks; PV interleaved per ks so only pf[4] is live.
// V staged from pre-transposed Vtg, XOR-chunk swizzled. LDS 32KB, 2 blk/CU.
__global__ __launch_bounds__(256, 2)
void k_attn(const u16* __restrict__ qkv, const u16* __restrict__ vtg,
            u16* __restrict__ mh) {
  __shared__ __align__(16) u16 smem[16384];
  u16* const Klds = smem;          // 128 keys x 8 chunks(8 u16), chunk-swizzled
  u16* const Vlds = smem + 8192;   // 64 e x 16 chunks, chunk-swizzled

  const int t = threadIdx.x;
  const int lane = t & 63;
  const int w = t >> 6;
  const int l15 = lane & 15;
  const int quad = lane >> 4;
  const int bh = blockIdx.y, b = bh >> 4, h = bh & 15;
  const int s0 = blockIdx.x << 8;   // 256 q rows per block

  // staging sources for slots s = t + r*256 (kt advanced by pointer bump)
  const u16* ksrc[4];
  const u16* vsrc[4];
  u16* dstK[4]; u16* dstV[4];
#pragma unroll
  for (int r = 0; r < 4; ++r) {
    const int s = t + r * 256;
    {  // K: row lam -> global key pi(lam), chunk c = cs ^ (lam&7)
      const int lam = s >> 3, cs = s & 7, c = cs ^ (lam & 7);
      const int key = (lam & 0x63) | (((lam >> 2) & 3) << 3) | (((lam >> 4) & 1) << 2);
      ksrc[r] = qkv + (size_t)(b * 2048 + key) * 3072 + 1024 + h * 64 + c * 8;
    }
    {  // V: row e, chunk c = cs ^ (e&15), plain key order
      const int e = s >> 4, cs = s & 15, c = cs ^ (e & 15);
      vsrc[r] = vtg + ((size_t)bh * 64 + e) * 2048 + c * 8;
    }
    dstK[r] = Klds + w * 512 + r * 2048;
    dstV[r] = Vlds + w * 512 + r * 2048;
  }

  // Q frags (B-operand) direct from global: q = w*64 + g*16 + l15
  bf16x8 aq[4][2];
#pragma unroll
  for (int g = 0; g < 4; ++g)
#pragma unroll
    for (int ks2 = 0; ks2 < 2; ++ks2)
      aq[g][ks2] = *(const bf16x8*)(qkv +
          (size_t)(b * 2048 + s0 + w * 64 + g * 16 + l15) * 3072 +
          h * 64 + ks2 * 32 + quad * 8);

  float lsum[4] = {0.f, 0.f, 0.f, 0.f};
  f32x4 o[4][4];
#pragma unroll
  for (int g = 0; g < 4; ++g)
#pragma unroll
    for (int ne = 0; ne < 4; ++ne) o[g][ne] = (f32x4){0.f, 0.f, 0.f, 0.f};

  for (int kt = 0; kt < 16; ++kt) {
    __syncthreads();  // prior tile reads done
#pragma unroll
    for (int r = 0; r < 4; ++r) { async16(ksrc[r], dstK[r]); ksrc[r] += 128 * 3072; }
#pragma unroll
    for (int r = 0; r < 4; ++r) { async16(vsrc[r], dstV[r]); vsrc[r] += 128; }
    __syncthreads();

#pragma unroll
    for (int ks = 0; ks < 4; ++ks) {
      u32x4 pf[4];  // per-g PV A-frag for key-chunk ks
#pragma unroll
      for (int h2 = 0; h2 < 2; ++h2) {
        const int kt8 = ks * 2 + h2;
        const int row = kt8 * 16 + l15;
        const bf16x8 kf0 = *(const bf16x8*)(Klds + row * 64 + ((quad) ^ (l15 & 7)) * 8);
        const bf16x8 kf1 = *(const bf16x8*)(Klds + row * 64 + ((4 + quad) ^ (l15 & 7)) * 8);
        f32x4 st[4];
#pragma unroll
        for (int g = 0; g < 4; ++g) {
          st[g] = __builtin_amdgcn_mfma_f32_16x16x32_bf16(kf0, aq[g][0], (f32x4){0.f,0.f,0.f,0.f}, 0, 0, 0);
          st[g] = __builtin_amdgcn_mfma_f32_16x16x32_bf16(kf1, aq[g][1], st[g], 0, 0, 0);
        }
#pragma unroll
        for (int g = 0; g < 4; ++g) {
          const float p0 = ex2(st[g][0]), p1 = ex2(st[g][1]);
          const float p2 = ex2(st[g][2]), p3 = ex2(st[g][3]);
          lsum[g] += (p0 + p1) + (p2 + p3);
          pf[g][h2 * 2 + 0] = pk2(p0, p1);
          pf[g][h2 * 2 + 1] = pk2(p2, p3);
        }
      }
#pragma unroll
      for (int ne = 0; ne < 4; ++ne) {
        const int e = ne * 16 + l15;
        const bf16x8 bv8 = *(const bf16x8*)(Vlds + e * 128 + (((ks * 4 + quad) ^ l15) & 15) * 8);
#pragma unroll
        for (int g = 0; g < 4; ++g)
          o[g][ne] = __builtin_amdgcn_mfma_f32_16x16x32_bf16(
              __builtin_bit_cast(bf16x8, pf[g]), bv8, o[g][ne], 0, 0, 0);
      }
    }
  }

  // l: partial per (quad,l15) -> reduce across quads (replicated), invert
  float inv[4];
#pragma unroll
  for (int g = 0; g < 4; ++g) {
    lsum[g] += __shfl_xor(lsum[g], 16);
    lsum[g] += __shfl_xor(lsum[g], 32);
    inv[g] = 1.f / lsum[g];
  }

  // epilogue: O row = quad*4+r within group; inv for that q sits at lane l15=q
#pragma unroll
  for (int g = 0; g < 4; ++g) {
#pragma unroll
    for (int r = 0; r < 4; ++r) {
      const float iv = __shfl(inv[g], quad * 4 + r);
      const int row = s0 + w * 64 + g * 16 + quad * 4 + r;
#pragma unroll
      for (int ne = 0; ne < 4; ++ne) {
        const int col = h * 64 + ne * 16 + l15;
        mh[(size_t)(b * 2048 + row) * 1024 + col] = f2bf(o[g][ne][r] * iv);
      }
    }
  }
}

// ---------------------------------------------------------------- launch ----
extern "C" void kernel_launch(void* const* d_in, const int* in_sizes, int n_in,
                              void* d_out, int out_size, void* d_ws, size_t ws_size,
                              hipStream_t stream) {
  (void)in_sizes; (void)n_in; (void)out_size; (void)ws_size;
  const float* x  = (const float*)d_in[0];
  const float* Wq = (const float*)d_in[1];
  const float* bq = (const float*)d_in[2];
  const float* Wk = (const float*)d_in[3];
  const float* bk = (const float*)d_in[4];
  const float* Wv = (const float*)d_in[5];
  const float* bv = (const float*)d_in[6];
  const float* Wo = (const float*)d_in[7];
  const float* bo = (const float*)d_in[8];

  char* ws = (char*)d_ws;
  u16*   Xb   = (u16*)  (ws + 0);          // 16777216 B (dead after gemm_qkv)
  u16*   Vtg  = (u16*)  (ws + 0);          // aliases Xb, written after
  u16*   Wt   = (u16*)  (ws + 16777216);   //  6291456
  float* bqkv = (float*)(ws + 23068672);   //    12288
  u16*   Wot  = (u16*)  (ws + 23080960);   //  2097152
  u16*   QKV  = (u16*)  (ws + 25178112);   // 50331648
  u16*   MH   = (u16*)  (ws + 75509760);   // 16777216  (total ~92.3 MB)
  float* out  = (float*)d_out;

  k_pack_all <<<12300, 256, 0, stream>>>(x, Wq, Wk, Wv, bq, bk, bv, Wo,
                                         Xb, Wt, bqkv, Wot);
  k_gemm<0>  <<<dim3(24, 64), 256, 0, stream>>>(Xb, Wt, bqkv, (void*)QKV, 3072);
  k_vt       <<<dim3(32, 64), 256, 0, stream>>>(QKV, Vtg);
  k_attn     <<<dim3(8, 64), 256, 0, stream>>>(QKV, Vtg, MH);
  k_gemm<1>  <<<dim3(8, 64), 256, 0, stream>>>(MH, Wot, bo, (void*)out, 1024);
}

// Round 5
// 341.135 us; speedup vs baseline: 1.0909x; 1.0909x over previous
//
#include <hip/hip_runtime.h>
#include <hip/hip_bf16.h>
#include <cstdint>
#include <cstddef>

// B=4, S=2048, D=1024, H=16, DH=64.  BS = 8192 rows.
// pack_all: x->bf16; Wqkv -> [3072 n][1024 k] bf16; bias pack; Wo -> [1024][1024]
// gemm_qkv: QKV[8192][3072] bf16 (Q cols pre-scaled by 0.125*log2(e), bias folded)
// vt: V part of QKV -> Vtg[bh=64][e=64][s=2048] bf16 (global transpose)
// attn: flash, S^T trick, exp2 domain -> MH [8192][1024] bf16
// gemm_out: out[8192][1024] f32 = MH @ Wo^T + bo

typedef unsigned short u16;
typedef unsigned int u32;
typedef __attribute__((ext_vector_type(8))) __bf16 bf16x8;
typedef __attribute__((ext_vector_type(8))) unsigned short u16x8;
typedef __attribute__((ext_vector_type(4))) float f32x4;
typedef __attribute__((ext_vector_type(4))) unsigned int u32x4;

__device__ __forceinline__ u16 f2bf(float f) {
  union { __hip_bfloat16 h; u16 u; } c;
  c.h = __float2bfloat16(f);
  return c.u;
}
__device__ __forceinline__ u32 pk2(float a, float b) {
  return (u32)f2bf(a) | ((u32)f2bf(b) << 16);
}
// exp2 via the amdgcn builtin (v_exp_f32). NOTE: __exp2f collides with a
// glibc math.h macro in this env — do not use it.
__device__ __forceinline__ float ex2(float x) {
  return __builtin_amdgcn_exp2f(x);
}

// async 16B global->LDS; LDS dest is wave-uniform base + lane*16.
__device__ __forceinline__ void async16(const void* g, void* l) {
  __builtin_amdgcn_global_load_lds(
      (const __attribute__((address_space(1))) void*)g,
      (__attribute__((address_space(3))) void*)l, 16, 0, 0);
}

// --------------------------------------------------------- merged packs ----
// grid: [0,8192) x->bf16 | [8192,11264) Wqkv | [11264,11276) bias | rest Wo
__global__ void k_pack_all(const float* __restrict__ x,
                           const float* __restrict__ Wq, const float* __restrict__ Wk,
                           const float* __restrict__ Wv,
                           const float* __restrict__ bq, const float* __restrict__ bk,
                           const float* __restrict__ bv,
                           const float* __restrict__ Wo,
                           u16* __restrict__ xb, u16* __restrict__ Wt,
                           float* __restrict__ bqkv, u16* __restrict__ Wot) {
  const int bid = blockIdx.x;
  if (bid < 8192) {
    const int i = (bid * 256 + threadIdx.x) * 4;
    const float4 v = *(const float4*)(x + i);
    ushort4 o;
    o.x = f2bf(v.x); o.y = f2bf(v.y); o.z = f2bf(v.z); o.w = f2bf(v.w);
    *(ushort4*)(xb + i) = o;
  } else if (bid < 11264) {
    const int gid = (bid - 8192) * 256 + threadIdx.x;
    const int n = gid >> 8;
    const int d0 = (gid & 255) << 2;
    const int proj = n >> 10, rem = n & 1023, h = rem >> 6, e = rem & 63;
    const float* Wp = (proj == 0) ? Wq : ((proj == 1) ? Wk : Wv);
    const float* src = Wp + h * 65536 + e;
    ushort4 o;
    o.x = f2bf(src[(d0 + 0) * 64]);
    o.y = f2bf(src[(d0 + 1) * 64]);
    o.z = f2bf(src[(d0 + 2) * 64]);
    o.w = f2bf(src[(d0 + 3) * 64]);
    *(ushort4*)(Wt + (size_t)n * 1024 + d0) = o;
  } else if (bid < 11276) {
    const int n = (bid - 11264) * 256 + threadIdx.x;
    const int proj = n >> 10, rem = n & 1023, h = rem >> 6, e = rem & 63;
    const float* bp = (proj == 0) ? bq : ((proj == 1) ? bk : bv);
    bqkv[n] = bp[h * 64 + e];
  } else {
    const int gid = (bid - 11276) * 256 + threadIdx.x;
    const int n = gid >> 8;
    const int d0 = (gid & 255) << 2;
    ushort4 o;
    o.x = f2bf(Wo[(size_t)(d0 + 0) * 1024 + n]);
    o.y = f2bf(Wo[(size_t)(d0 + 1) * 1024 + n]);
    o.z = f2bf(Wo[(size_t)(d0 + 2) * 1024 + n]);
    o.w = f2bf(Wo[(size_t)(d0 + 3) * 1024 + n]);
    *(ushort4*)(Wot + (size_t)n * 1024 + d0) = o;
  }
}

// ----------------------------------------------------------------- GEMM ----
// (m97 structure). MODE 0: bf16 out, Q cols scaled by 0.125*log2e (exp2 domain).
template <int MODE>
__global__ __launch_bounds__(256)
void k_gemm(const u16* __restrict__ A, const u16* __restrict__ Bt,
            const float* __restrict__ bias, void* __restrict__ Cout, int ldc) {
  __shared__ __align__(16) u16 Alds[128 * 32];
  __shared__ __align__(16) u16 Blds[128 * 32];
  const int t = threadIdx.x;
  const int lane = t & 63;
  const int w = t >> 6;
  const int l15 = lane & 15;
  const int quad = lane >> 4;
  const int wm = w >> 1, wn = w & 1;
  const int m0 = blockIdx.y << 7;
  const int n0 = blockIdx.x << 7;

  const u16* ga0 = A + (size_t)(m0 + (t >> 2)) * 1024 + (t & 3) * 8;
  const u16* ga1 = ga0 + (size_t)64 * 1024;
  const u16* gb0 = Bt + (size_t)(n0 + (t >> 2)) * 1024 + (t & 3) * 8;
  const u16* gb1 = gb0 + (size_t)64 * 1024;
  u16* const lA0 = Alds + w * 512;
  u16* const lA1 = Alds + w * 512 + 2048;
  u16* const lB0 = Blds + w * 512;
  u16* const lB1 = Blds + w * 512 + 2048;

  f32x4 acc[4][4];
#pragma unroll
  for (int mi = 0; mi < 4; ++mi)
#pragma unroll
    for (int ni = 0; ni < 4; ++ni) acc[mi][ni] = (f32x4){0.f, 0.f, 0.f, 0.f};

  for (int k0 = 0; k0 < 1024; k0 += 32) {
    __syncthreads();
    async16(ga0, lA0); async16(ga1, lA1);
    async16(gb0, lB0); async16(gb1, lB1);
    ga0 += 32; ga1 += 32; gb0 += 32; gb1 += 32;
    __syncthreads();
    bf16x8 af[4], bfr[4];
#pragma unroll
    for (int i = 0; i < 4; ++i) {
      af[i]  = *(const bf16x8*)(Alds + (wm * 64 + i * 16 + l15) * 32 + quad * 8);
      bfr[i] = *(const bf16x8*)(Blds + (wn * 64 + i * 16 + l15) * 32 + quad * 8);
    }
#pragma unroll
    for (int mi = 0; mi < 4; ++mi)
#pragma unroll
      for (int ni = 0; ni < 4; ++ni)
        acc[mi][ni] = __builtin_amdgcn_mfma_f32_16x16x32_bf16(af[mi], bfr[ni], acc[mi][ni], 0, 0, 0);
  }

  const int row0 = m0 + wm * 64;
  const int col0 = n0 + wn * 64;
  // Q prescale: 1/sqrt(64) * log2(e) so attention can use bare v_exp_f32 (exp2)
  const float qscale = (MODE == 0 && col0 < 1024) ? 0.125f * 1.4426950408889634f : 1.0f;
#pragma unroll
  for (int mi = 0; mi < 4; ++mi) {
#pragma unroll
    for (int ni = 0; ni < 4; ++ni) {
      const int col = col0 + ni * 16 + l15;
      const float bb = bias[col];
#pragma unroll
      for (int r = 0; r < 4; ++r) {
        const int row = row0 + mi * 16 + quad * 4 + r;
        const float v = (acc[mi][ni][r] + bb) * qscale;
        if (MODE == 0) ((u16*)Cout)[(size_t)row * ldc + col] = f2bf(v);
        else           ((float*)Cout)[(size_t)row * ldc + col] = v;
      }
    }
  }
}

// ------------------------------------------------- V global transpose ----
// Vtg[bh][e][s] = QKV[b*2048+s][2048 + h*64 + e]
__global__ __launch_bounds__(256)
void k_vt(const u16* __restrict__ qkv, u16* __restrict__ vtg) {
  __shared__ u16 tile[64][72];
  const int t = threadIdx.x;
  const int bh = blockIdx.y, b = bh >> 4, h = bh & 15;
  const int s0 = blockIdx.x << 6;
  {
    const int row = t >> 2, col0 = (t & 3) * 16;
    const u16* src = qkv + (size_t)(b * 2048 + s0 + row) * 3072 + 2048 + h * 64 + col0;
    const u16x8 v0 = *(const u16x8*)src;
    const u16x8 v1 = *(const u16x8*)(src + 8);
    *(u16x8*)&tile[row][col0] = v0;
    *(u16x8*)&tile[row][col0 + 8] = v1;
  }
  __syncthreads();
  {
    const int e = t >> 2, sc = (t & 3) * 16;
    u16 buf[16];
#pragma unroll
    for (int i = 0; i < 16; ++i) buf[i] = tile[sc + i][e];
    u16* dst = vtg + ((size_t)bh * 64 + e) * 2048 + s0 + sc;
    *(u16x8*)dst = *(const u16x8*)&buf[0];
    *(u16x8*)(dst + 8) = *(const u16x8*)&buf[8];
  }
}

// ------------------------------------------------------------- attention ----
// Block = (bh, 256 q rows), 4 waves x 64 q each (4 groups of 16).
// Per K-tile (128 keys): S^T = K.Q^T (A = K-frags from LDS under permutation
// pi; B = Q-frags in regs). Scores in log2-domain -> p = exp2(s). Packed
// exp2 register pairs ARE the PV A-fragment for key-chunk ks; PV interleaved
// per ks so only pf[4] is live. V staged from pre-transposed Vtg.
// Register note: live set ~170 VGPRs (o=64 acc, aq=32, temps). NO min-waves
// clause in launch_bounds — (256,2) clamped the file to 128 and spilled
// ~18 regs/lane/iter to scratch (R4: WRITE_SIZE 16->171 MB). Plain (256)
// lets the allocator take ~190 and still fit 2 waves/SIMD.
// r-strides are constant: pi puts r in key bits 5-6 (ksrc0 + r*32*3072);
// V's chunk xor is r-invariant (vsrc0 + r*16*2048) — 2 live base pointers.
__global__ __launch_bounds__(256)
void k_attn(const u16* __restrict__ qkv, const u16* __restrict__ vtg,
            u16* __restrict__ mh) {
  __shared__ __align__(16) u16 smem[16384];
  u16* const Klds = smem;          // 128 keys x 8 chunks(8 u16), chunk-swizzled
  u16* const Vlds = smem + 8192;   // 64 e x 16 chunks, chunk-swizzled

  const int t = threadIdx.x;
  const int lane = t & 63;
  const int w = t >> 6;
  const int l15 = lane & 15;
  const int quad = lane >> 4;
  const int bh = blockIdx.y, b = bh >> 4, h = bh & 15;
  const int s0 = blockIdx.x << 8;   // 256 q rows per block

  // K staging base (r=0): lam0 = t>>3 in [0,32), key0 = pi(lam0) (bits 5,6 = 0)
  const int lam0 = t >> 3;
  const int key0 = (lam0 & 3) | (((lam0 >> 2) & 3) << 3) | (((lam0 >> 4) & 1) << 2);
  const int ck = (t & 7) ^ (lam0 & 7);
  const u16* kbase = qkv + (size_t)(b * 2048 + key0) * 3072 + 1024 + h * 64 + ck * 8;
  // V staging base (r=0): e0 = t>>4 in [0,16), chunk = (t&15) ^ e0
  const int e0 = t >> 4;
  const int cv = (t & 15) ^ e0;
  const u16* vbase = vtg + ((size_t)bh * 64 + e0) * 2048 + cv * 8;
  u16* const KldsW = Klds + w * 512;
  u16* const VldsW = Vlds + w * 512;

  // Q frags (B-operand) direct from global: q = w*64 + g*16 + l15
  bf16x8 aq[4][2];
#pragma unroll
  for (int g = 0; g < 4; ++g)
#pragma unroll
    for (int ks2 = 0; ks2 < 2; ++ks2)
      aq[g][ks2] = *(const bf16x8*)(qkv +
          (size_t)(b * 2048 + s0 + w * 64 + g * 16 + l15) * 3072 +
          h * 64 + ks2 * 32 + quad * 8);

  float lsum[4] = {0.f, 0.f, 0.f, 0.f};
  f32x4 o[4][4];
#pragma unroll
  for (int g = 0; g < 4; ++g)
#pragma unroll
    for (int ne = 0; ne < 4; ++ne) o[g][ne] = (f32x4){0.f, 0.f, 0.f, 0.f};

  for (int kt = 0; kt < 16; ++kt) {
    __syncthreads();  // prior tile reads done
#pragma unroll
    for (int r = 0; r < 4; ++r)
      async16(kbase + r * (32 * 3072), KldsW + r * 2048);
#pragma unroll
    for (int r = 0; r < 4; ++r)
      async16(vbase + r * (16 * 2048), VldsW + r * 2048);
    kbase += 128 * 3072;
    vbase += 128;
    __syncthreads();

#pragma unroll
    for (int ks = 0; ks < 4; ++ks) {
      u32x4 pf[4];  // per-g PV A-frag for key-chunk ks
#pragma unroll
      for (int h2 = 0; h2 < 2; ++h2) {
        const int kt8 = ks * 2 + h2;
        const int row = kt8 * 16 + l15;
        const bf16x8 kf0 = *(const bf16x8*)(Klds + row * 64 + ((quad) ^ (l15 & 7)) * 8);
        const bf16x8 kf1 = *(const bf16x8*)(Klds + row * 64 + ((4 + quad) ^ (l15 & 7)) * 8);
        f32x4 st[4];
#pragma unroll
        for (int g = 0; g < 4; ++g) {
          st[g] = __builtin_amdgcn_mfma_f32_16x16x32_bf16(kf0, aq[g][0], (f32x4){0.f,0.f,0.f,0.f}, 0, 0, 0);
          st[g] = __builtin_amdgcn_mfma_f32_16x16x32_bf16(kf1, aq[g][1], st[g], 0, 0, 0);
        }
#pragma unroll
        for (int g = 0; g < 4; ++g) {
          const float p0 = ex2(st[g][0]), p1 = ex2(st[g][1]);
          const float p2 = ex2(st[g][2]), p3 = ex2(st[g][3]);
          lsum[g] += (p0 + p1) + (p2 + p3);
          pf[g][h2 * 2 + 0] = pk2(p0, p1);
          pf[g][h2 * 2 + 1] = pk2(p2, p3);
        }
      }
#pragma unroll
      for (int ne = 0; ne < 4; ++ne) {
        const int e = ne * 16 + l15;
        const bf16x8 bv8 = *(const bf16x8*)(Vlds + e * 128 + (((ks * 4 + quad) ^ l15) & 15) * 8);
#pragma unroll
        for (int g = 0; g < 4; ++g)
          o[g][ne] = __builtin_amdgcn_mfma_f32_16x16x32_bf16(
              __builtin_bit_cast(bf16x8, pf[g]), bv8, o[g][ne], 0, 0, 0);
      }
    }
  }

  // l: partial per (quad,l15) -> reduce across quads (replicated), invert
  float inv[4];
#pragma unroll
  for (int g = 0; g < 4; ++g) {
    lsum[g] += __shfl_xor(lsum[g], 16);
    lsum[g] += __shfl_xor(lsum[g], 32);
    inv[g] = 1.f / lsum[g];
  }

  // epilogue: O row = quad*4+r within group; inv for that q sits at lane l15=q
#pragma unroll
  for (int g = 0; g < 4; ++g) {
#pragma unroll
    for (int r = 0; r < 4; ++r) {
      const float iv = __shfl(inv[g], quad * 4 + r);
      const int row = s0 + w * 64 + g * 16 + quad * 4 + r;
#pragma unroll
      for (int ne = 0; ne < 4; ++ne) {
        const int col = h * 64 + ne * 16 + l15;
        mh[(size_t)(b * 2048 + row) * 1024 + col] = f2bf(o[g][ne][r] * iv);
      }
    }
  }
}

// ---------------------------------------------------------------- launch ----
extern "C" void kernel_launch(void* const* d_in, const int* in_sizes, int n_in,
                              void* d_out, int out_size, void* d_ws, size_t ws_size,
                              hipStream_t stream) {
  (void)in_sizes; (void)n_in; (void)out_size; (void)ws_size;
  const float* x  = (const float*)d_in[0];
  const float* Wq = (const float*)d_in[1];
  const float* bq = (const float*)d_in[2];
  const float* Wk = (const float*)d_in[3];
  const float* bk = (const float*)d_in[4];
  const float* Wv = (const float*)d_in[5];
  const float* bv = (const float*)d_in[6];
  const float* Wo = (const float*)d_in[7];
  const float* bo = (const float*)d_in[8];

  char* ws = (char*)d_ws;
  u16*   Xb   = (u16*)  (ws + 0);          // 16777216 B (dead after gemm_qkv)
  u16*   Vtg  = (u16*)  (ws + 0);          // aliases Xb, written after
  u16*   Wt   = (u16*)  (ws + 16777216);   //  6291456
  float* bqkv = (float*)(ws + 23068672);   //    12288
  u16*   Wot  = (u16*)  (ws + 23080960);   //  2097152
  u16*   QKV  = (u16*)  (ws + 25178112);   // 50331648
  u16*   MH   = (u16*)  (ws + 75509760);   // 16777216  (total ~92.3 MB)
  float* out  = (float*)d_out;

  k_pack_all <<<12300, 256, 0, stream>>>(x, Wq, Wk, Wv, bq, bk, bv, Wo,
                                         Xb, Wt, bqkv, Wot);
  k_gemm<0>  <<<dim3(24, 64), 256, 0, stream>>>(Xb, Wt, bqkv, (void*)QKV, 3072);
  k_vt       <<<dim3(32, 64), 256, 0, stream>>>(QKV, Vtg);
  k_attn     <<<dim3(8, 64), 256, 0, stream>>>(QKV, Vtg, MH);
  k_gemm<1>  <<<dim3(8, 64), 256, 0, stream>>>(MH, Wot, bo, (void*)out, 1024);
}

// Round 6
// 319.466 us; speedup vs baseline: 1.1649x; 1.0678x over previous
//
#include <hip/hip_runtime.h>
#include <hip/hip_bf16.h>
#include <cstdint>
#include <cstddef>

// B=4, S=2048, D=1024, H=16, DH=64.  BS = 8192 rows.
// pack_all: x->bf16; Wqkv -> [3072 n][1024 k] bf16; bias pack; Wo -> [1024][1024]
// gemm_qkv: QKV[8192][3072] bf16 (Q cols pre-scaled by 0.125*log2(e), bias folded)
// vt: V part of QKV -> Vtg[bh=64][e=64][s=2048] bf16 (global transpose)
// attn: flash, S^T trick, exp2 domain, l-via-MFMA -> MH [8192][1024] bf16
// gemm_out: out[8192][1024] f32 = MH @ Wo^T + bo

typedef unsigned short u16;
typedef unsigned int u32;
typedef __attribute__((ext_vector_type(8))) __bf16 bf16x8;
typedef __attribute__((ext_vector_type(8))) unsigned short u16x8;
typedef __attribute__((ext_vector_type(4))) float f32x4;
typedef __attribute__((ext_vector_type(4))) unsigned int u32x4;

__device__ __forceinline__ u16 f2bf(float f) {
  union { __hip_bfloat16 h; u16 u; } c;
  c.h = __float2bfloat16(f);
  return c.u;
}
// Cheap RNE bf16 pack for values known finite & normal (exp2 outputs).
// Bit-identical to __float2bfloat16 RNE for such values, ~5 VALU per pair
// vs ~15 (skips NaN handling). low16(dst)=bf16(a), high16(dst)=bf16(b).
__device__ __forceinline__ u32 pk2c(float a, float b) {
  const u32 ua = __float_as_uint(a);
  const u32 ub = __float_as_uint(b);
  const u32 ra = ua + 0x7FFFu + ((ua >> 16) & 1u);
  const u32 rb = ub + 0x7FFFu + ((ub >> 16) & 1u);
  return (ra >> 16) | (rb & 0xFFFF0000u);
}
// exp2 via the amdgcn builtin (v_exp_f32). NOTE: __exp2f collides with a
// glibc math.h macro in this env — do not use it.
__device__ __forceinline__ float ex2(float x) {
  return __builtin_amdgcn_exp2f(x);
}

// async 16B global->LDS; LDS dest is wave-uniform base + lane*16.
__device__ __forceinline__ void async16(const void* g, void* l) {
  __builtin_amdgcn_global_load_lds(
      (const __attribute__((address_space(1))) void*)g,
      (__attribute__((address_space(3))) void*)l, 16, 0, 0);
}

// --------------------------------------------------------- merged packs ----
// grid: [0,8192) x->bf16 | [8192,11264) Wqkv | [11264,11276) bias | rest Wo
__global__ void k_pack_all(const float* __restrict__ x,
                           const float* __restrict__ Wq, const float* __restrict__ Wk,
                           const float* __restrict__ Wv,
                           const float* __restrict__ bq, const float* __restrict__ bk,
                           const float* __restrict__ bv,
                           const float* __restrict__ Wo,
                           u16* __restrict__ xb, u16* __restrict__ Wt,
                           float* __restrict__ bqkv, u16* __restrict__ Wot) {
  const int bid = blockIdx.x;
  if (bid < 8192) {
    const int i = (bid * 256 + threadIdx.x) * 4;
    const float4 v = *(const float4*)(x + i);
    ushort4 o;
    o.x = f2bf(v.x); o.y = f2bf(v.y); o.z = f2bf(v.z); o.w = f2bf(v.w);
    *(ushort4*)(xb + i) = o;
  } else if (bid < 11264) {
    const int gid = (bid - 8192) * 256 + threadIdx.x;
    const int n = gid >> 8;
    const int d0 = (gid & 255) << 2;
    const int proj = n >> 10, rem = n & 1023, h = rem >> 6, e = rem & 63;
    const float* Wp = (proj == 0) ? Wq : ((proj == 1) ? Wk : Wv);
    const float* src = Wp + h * 65536 + e;
    ushort4 o;
    o.x = f2bf(src[(d0 + 0) * 64]);
    o.y = f2bf(src[(d0 + 1) * 64]);
    o.z = f2bf(src[(d0 + 2) * 64]);
    o.w = f2bf(src[(d0 + 3) * 64]);
    *(ushort4*)(Wt + (size_t)n * 1024 + d0) = o;
  } else if (bid < 11276) {
    const int n = (bid - 11264) * 256 + threadIdx.x;
    const int proj = n >> 10, rem = n & 1023, h = rem >> 6, e = rem & 63;
    const float* bp = (proj == 0) ? bq : ((proj == 1) ? bk : bv);
    bqkv[n] = bp[h * 64 + e];
  } else {
    const int gid = (bid - 11276) * 256 + threadIdx.x;
    const int n = gid >> 8;
    const int d0 = (gid & 255) << 2;
    ushort4 o;
    o.x = f2bf(Wo[(size_t)(d0 + 0) * 1024 + n]);
    o.y = f2bf(Wo[(size_t)(d0 + 1) * 1024 + n]);
    o.z = f2bf(Wo[(size_t)(d0 + 2) * 1024 + n]);
    o.w = f2bf(Wo[(size_t)(d0 + 3) * 1024 + n]);
    *(ushort4*)(Wot + (size_t)n * 1024 + d0) = o;
  }
}

// ----------------------------------------------------------------- GEMM ----
// (m97 structure). MODE 0: bf16 out, Q cols scaled by 0.125*log2e (exp2 domain).
template <int MODE>
__global__ __launch_bounds__(256)
void k_gemm(const u16* __restrict__ A, const u16* __restrict__ Bt,
            const float* __restrict__ bias, void* __restrict__ Cout, int ldc) {
  __shared__ __align__(16) u16 Alds[128 * 32];
  __shared__ __align__(16) u16 Blds[128 * 32];
  const int t = threadIdx.x;
  const int lane = t & 63;
  const int w = t >> 6;
  const int l15 = lane & 15;
  const int quad = lane >> 4;
  const int wm = w >> 1, wn = w & 1;
  const int m0 = blockIdx.y << 7;
  const int n0 = blockIdx.x << 7;

  const u16* ga0 = A + (size_t)(m0 + (t >> 2)) * 1024 + (t & 3) * 8;
  const u16* ga1 = ga0 + (size_t)64 * 1024;
  const u16* gb0 = Bt + (size_t)(n0 + (t >> 2)) * 1024 + (t & 3) * 8;
  const u16* gb1 = gb0 + (size_t)64 * 1024;
  u16* const lA0 = Alds + w * 512;
  u16* const lA1 = Alds + w * 512 + 2048;
  u16* const lB0 = Blds + w * 512;
  u16* const lB1 = Blds + w * 512 + 2048;

  f32x4 acc[4][4];
#pragma unroll
  for (int mi = 0; mi < 4; ++mi)
#pragma unroll
    for (int ni = 0; ni < 4; ++ni) acc[mi][ni] = (f32x4){0.f, 0.f, 0.f, 0.f};

  for (int k0 = 0; k0 < 1024; k0 += 32) {
    __syncthreads();
    async16(ga0, lA0); async16(ga1, lA1);
    async16(gb0, lB0); async16(gb1, lB1);
    ga0 += 32; ga1 += 32; gb0 += 32; gb1 += 32;
    __syncthreads();
    bf16x8 af[4], bfr[4];
#pragma unroll
    for (int i = 0; i < 4; ++i) {
      af[i]  = *(const bf16x8*)(Alds + (wm * 64 + i * 16 + l15) * 32 + quad * 8);
      bfr[i] = *(const bf16x8*)(Blds + (wn * 64 + i * 16 + l15) * 32 + quad * 8);
    }
#pragma unroll
    for (int mi = 0; mi < 4; ++mi)
#pragma unroll
      for (int ni = 0; ni < 4; ++ni)
        acc[mi][ni] = __builtin_amdgcn_mfma_f32_16x16x32_bf16(af[mi], bfr[ni], acc[mi][ni], 0, 0, 0);
  }

  const int row0 = m0 + wm * 64;
  const int col0 = n0 + wn * 64;
  // Q prescale: 1/sqrt(64) * log2(e) so attention can use bare v_exp_f32 (exp2)
  const float qscale = (MODE == 0 && col0 < 1024) ? 0.125f * 1.4426950408889634f : 1.0f;
#pragma unroll
  for (int mi = 0; mi < 4; ++mi) {
#pragma unroll
    for (int ni = 0; ni < 4; ++ni) {
      const int col = col0 + ni * 16 + l15;
      const float bb = bias[col];
#pragma unroll
      for (int r = 0; r < 4; ++r) {
        const int row = row0 + mi * 16 + quad * 4 + r;
        const float v = (acc[mi][ni][r] + bb) * qscale;
        if (MODE == 0) ((u16*)Cout)[(size_t)row * ldc + col] = f2bf(v);
        else           ((float*)Cout)[(size_t)row * ldc + col] = v;
      }
    }
  }
}

// ------------------------------------------------- V global transpose ----
// Vtg[bh][e][s] = QKV[b*2048+s][2048 + h*64 + e]
__global__ __launch_bounds__(256)
void k_vt(const u16* __restrict__ qkv, u16* __restrict__ vtg) {
  __shared__ u16 tile[64][72];
  const int t = threadIdx.x;
  const int bh = blockIdx.y, b = bh >> 4, h = bh & 15;
  const int s0 = blockIdx.x << 6;
  {
    const int row = t >> 2, col0 = (t & 3) * 16;
    const u16* src = qkv + (size_t)(b * 2048 + s0 + row) * 3072 + 2048 + h * 64 + col0;
    const u16x8 v0 = *(const u16x8*)src;
    const u16x8 v1 = *(const u16x8*)(src + 8);
    *(u16x8*)&tile[row][col0] = v0;
    *(u16x8*)&tile[row][col0 + 8] = v1;
  }
  __syncthreads();
  {
    const int e = t >> 2, sc = (t & 3) * 16;
    u16 buf[16];
#pragma unroll
    for (int i = 0; i < 16; ++i) buf[i] = tile[sc + i][e];
    u16* dst = vtg + ((size_t)bh * 64 + e) * 2048 + s0 + sc;
    *(u16x8*)dst = *(const u16x8*)&buf[0];
    *(u16x8*)(dst + 8) = *(const u16x8*)&buf[8];
  }
}

// ------------------------------------------------------------- attention ----
// Block = (bh, 128 q rows), 4 waves x 32 q each (2 groups of 16).
// Grid 1024 = 4 blocks/CU (R5's 512-block grid was latency-bound at 11% occ).
// Per K-tile (128 keys): S^T = K.Q^T (A = K-frags from LDS under permutation
// pi; B = Q-frags in regs). Scores in log2-domain -> p = exp2(s). Packed
// exp2 register pairs ARE the PV A-fragment for key-chunk ks.
// l is computed BY MFMA (B = all-ones frag): lacc[g][r] = sum_key P[q][key]
// lands in the same row layout as o -> no VALU lsum adds, no shuffles.
// Register note: plain launch_bounds(256) — a min-waves clause clamped the
// unified VGPR file and spilled (R4: WRITE_SIZE 16->171 MB). Live set here
// ~115 regs -> 4 waves/SIMD naturally.
__global__ __launch_bounds__(256)
void k_attn(const u16* __restrict__ qkv, const u16* __restrict__ vtg,
            u16* __restrict__ mh) {
  __shared__ __align__(16) u16 smem[16384];
  u16* const Klds = smem;          // 128 keys x 8 chunks(8 u16), chunk-swizzled
  u16* const Vlds = smem + 8192;   // 64 e x 16 chunks, chunk-swizzled

  const int t = threadIdx.x;
  const int lane = t & 63;
  const int w = t >> 6;
  const int l15 = lane & 15;
  const int quad = lane >> 4;
  const int bh = blockIdx.y, b = bh >> 4, h = bh & 15;
  const int s0 = blockIdx.x << 7;   // 128 q rows per block

  // K staging base (r=0): lam0 = t>>3 in [0,32), key0 = pi(lam0) (bits 5,6 = 0)
  const int lam0 = t >> 3;
  const int key0 = (lam0 & 3) | (((lam0 >> 2) & 3) << 3) | (((lam0 >> 4) & 1) << 2);
  const int ck = (t & 7) ^ (lam0 & 7);
  const u16* kbase = qkv + (size_t)(b * 2048 + key0) * 3072 + 1024 + h * 64 + ck * 8;
  // V staging base (r=0): e0 = t>>4 in [0,16), chunk = (t&15) ^ e0
  const int e0 = t >> 4;
  const int cv = (t & 15) ^ e0;
  const u16* vbase = vtg + ((size_t)bh * 64 + e0) * 2048 + cv * 8;
  u16* const KldsW = Klds + w * 512;
  u16* const VldsW = Vlds + w * 512;

  // Q frags (B-operand) direct from global: q = w*32 + g*16 + l15
  bf16x8 aq[2][2];
#pragma unroll
  for (int g = 0; g < 2; ++g)
#pragma unroll
    for (int ks2 = 0; ks2 < 2; ++ks2)
      aq[g][ks2] = *(const bf16x8*)(qkv +
          (size_t)(b * 2048 + s0 + w * 32 + g * 16 + l15) * 3072 +
          h * 64 + ks2 * 32 + quad * 8);

  // all-ones B-frag for the l-MFMA (bf16 1.0 = 0x3F80)
  const u32x4 onesu = (u32x4){0x3F803F80u, 0x3F803F80u, 0x3F803F80u, 0x3F803F80u};
  const bf16x8 ones = __builtin_bit_cast(bf16x8, onesu);

  f32x4 o[2][4];
  f32x4 lacc[2];
#pragma unroll
  for (int g = 0; g < 2; ++g) {
    lacc[g] = (f32x4){0.f, 0.f, 0.f, 0.f};
#pragma unroll
    for (int ne = 0; ne < 4; ++ne) o[g][ne] = (f32x4){0.f, 0.f, 0.f, 0.f};
  }

  for (int kt = 0; kt < 16; ++kt) {
    __syncthreads();  // prior tile reads done
#pragma unroll
    for (int r = 0; r < 4; ++r)
      async16(kbase + r * (32 * 3072), KldsW + r * 2048);
#pragma unroll
    for (int r = 0; r < 4; ++r)
      async16(vbase + r * (16 * 2048), VldsW + r * 2048);
    kbase += 128 * 3072;
    vbase += 128;
    __syncthreads();

#pragma unroll
    for (int ks = 0; ks < 4; ++ks) {
      u32x4 pf[2];  // per-g PV A-frag for key-chunk ks
#pragma unroll
      for (int h2 = 0; h2 < 2; ++h2) {
        const int kt8 = ks * 2 + h2;
        const int row = kt8 * 16 + l15;
        const bf16x8 kf0 = *(const bf16x8*)(Klds + row * 64 + ((quad) ^ (l15 & 7)) * 8);
        const bf16x8 kf1 = *(const bf16x8*)(Klds + row * 64 + ((4 + quad) ^ (l15 & 7)) * 8);
        f32x4 st[2];
#pragma unroll
        for (int g = 0; g < 2; ++g) {
          st[g] = __builtin_amdgcn_mfma_f32_16x16x32_bf16(kf0, aq[g][0], (f32x4){0.f,0.f,0.f,0.f}, 0, 0, 0);
          st[g] = __builtin_amdgcn_mfma_f32_16x16x32_bf16(kf1, aq[g][1], st[g], 0, 0, 0);
        }
#pragma unroll
        for (int g = 0; g < 2; ++g) {
          const float p0 = ex2(st[g][0]), p1 = ex2(st[g][1]);
          const float p2 = ex2(st[g][2]), p3 = ex2(st[g][3]);
          pf[g][h2 * 2 + 0] = pk2c(p0, p1);
          pf[g][h2 * 2 + 1] = pk2c(p2, p3);
        }
      }
#pragma unroll
      for (int ne = 0; ne < 4; ++ne) {
        const int e = ne * 16 + l15;
        const bf16x8 bv8 = *(const bf16x8*)(Vlds + e * 128 + (((ks * 4 + quad) ^ l15) & 15) * 8);
#pragma unroll
        for (int g = 0; g < 2; ++g)
          o[g][ne] = __builtin_amdgcn_mfma_f32_16x16x32_bf16(
              __builtin_bit_cast(bf16x8, pf[g]), bv8, o[g][ne], 0, 0, 0);
      }
#pragma unroll
      for (int g = 0; g < 2; ++g)
        lacc[g] = __builtin_amdgcn_mfma_f32_16x16x32_bf16(
            __builtin_bit_cast(bf16x8, pf[g]), ones, lacc[g], 0, 0, 0);
    }
  }

  // epilogue: O row = quad*4+r within group; lacc has the SAME row layout,
  // so inv is per-(g,r) with no cross-lane traffic.
#pragma unroll
  for (int g = 0; g < 2; ++g) {
#pragma unroll
    for (int r = 0; r < 4; ++r) {
      const float iv = 1.f / lacc[g][r];
      const int row = s0 + w * 32 + g * 16 + quad * 4 + r;
#pragma unroll
      for (int ne = 0; ne < 4; ++ne) {
        const int col = h * 64 + ne * 16 + l15;
        mh[(size_t)(b * 2048 + row) * 1024 + col] = f2bf(o[g][ne][r] * iv);
      }
    }
  }
}

// ---------------------------------------------------------------- launch ----
extern "C" void kernel_launch(void* const* d_in, const int* in_sizes, int n_in,
                              void* d_out, int out_size, void* d_ws, size_t ws_size,
                              hipStream_t stream) {
  (void)in_sizes; (void)n_in; (void)out_size; (void)ws_size;
  const float* x  = (const float*)d_in[0];
  const float* Wq = (const float*)d_in[1];
  const float* bq = (const float*)d_in[2];
  const float* Wk = (const float*)d_in[3];
  const float* bk = (const float*)d_in[4];
  const float* Wv = (const float*)d_in[5];
  const float* bv = (const float*)d_in[6];
  const float* Wo = (const float*)d_in[7];
  const float* bo = (const float*)d_in[8];

  char* ws = (char*)d_ws;
  u16*   Xb   = (u16*)  (ws + 0);          // 16777216 B (dead after gemm_qkv)
  u16*   Vtg  = (u16*)  (ws + 0);          // aliases Xb, written after
  u16*   Wt   = (u16*)  (ws + 16777216);   //  6291456
  float* bqkv = (float*)(ws + 23068672);   //    12288
  u16*   Wot  = (u16*)  (ws + 23080960);   //  2097152
  u16*   QKV  = (u16*)  (ws + 25178112);   // 50331648
  u16*   MH   = (u16*)  (ws + 75509760);   // 16777216  (total ~92.3 MB)
  float* out  = (float*)d_out;

  k_pack_all <<<12300, 256, 0, stream>>>(x, Wq, Wk, Wv, bq, bk, bv, Wo,
                                         Xb, Wt, bqkv, Wot);
  k_gemm<0>  <<<dim3(24, 64), 256, 0, stream>>>(Xb, Wt, bqkv, (void*)QKV, 3072);
  k_vt       <<<dim3(32, 64), 256, 0, stream>>>(QKV, Vtg);
  k_attn     <<<dim3(16, 64), 256, 0, stream>>>(QKV, Vtg, MH);
  k_gemm<1>  <<<dim3(8, 64), 256, 0, stream>>>(MH, Wot, bo, (void*)out, 1024);
}

// Round 7
// 291.661 us; speedup vs baseline: 1.2759x; 1.0953x over previous
//
#include <hip/hip_runtime.h>
#include <hip/hip_bf16.h>
#include <cstdint>
#include <cstddef>

// B=4, S=2048, D=1024, H=16, DH=64.  BS = 8192 rows.
// pack_all: W transposes via LDS (coalesced), x->bf16, bias pack
// gemm_qkv: QKV[8192][3072] bf16 (Q cols pre-scaled by 0.125*log2(e), bias folded)
// vt: V part of QKV -> Vtg[bh=64][e=64][s=2048] bf16 (global transpose)
// attn: flash, S^T trick, exp2 domain, l-via-MFMA -> MH [8192][1024] bf16
// gemm_out: out[8192][1024] f32 = MH @ Wo^T + bo

typedef unsigned short u16;
typedef unsigned int u32;
typedef __attribute__((ext_vector_type(8))) __bf16 bf16x8;
typedef __attribute__((ext_vector_type(8))) unsigned short u16x8;
typedef __attribute__((ext_vector_type(4))) float f32x4;
typedef __attribute__((ext_vector_type(4))) unsigned int u32x4;

__device__ __forceinline__ u16 f2bf(float f) {
  union { __hip_bfloat16 h; u16 u; } c;
  c.h = __float2bfloat16(f);
  return c.u;
}
// Pack two f32 -> bf16x2 (RNE). Prefer the gfx950 HW instruction
// v_cvt_pk_bf16_f32 (1 VALU op); fallback: manual RNE (~6 VALU ops).
#if defined(__has_builtin)
#if __has_builtin(__builtin_amdgcn_cvt_pk_bf16_f32)
#define HAS_PK_BF16 1
#endif
#endif
__device__ __forceinline__ u32 pk2c(float a, float b) {
#ifdef HAS_PK_BF16
  return __builtin_bit_cast(u32, __builtin_amdgcn_cvt_pk_bf16_f32(a, b));
#else
  const u32 ua = __float_as_uint(a);
  const u32 ub = __float_as_uint(b);
  const u32 ra = ua + 0x7FFFu + ((ua >> 16) & 1u);
  const u32 rb = ub + 0x7FFFu + ((ub >> 16) & 1u);
  return (ra >> 16) | (rb & 0xFFFF0000u);
#endif
}
// exp2 via the amdgcn builtin (v_exp_f32). NOTE: __exp2f collides with a
// glibc math.h macro in this env — do not use it.
__device__ __forceinline__ float ex2(float x) {
  return __builtin_amdgcn_exp2f(x);
}

// async 16B global->LDS; LDS dest is wave-uniform base + lane*16.
__device__ __forceinline__ void async16(const void* g, void* l) {
  __builtin_amdgcn_global_load_lds(
      (const __attribute__((address_space(1))) void*)g,
      (__attribute__((address_space(3))) void*)l, 16, 0, 0);
}

// --------------------------------------------------------- merged packs ----
// grid [0,1024): 64x64 f32->bf16 LDS transposes (768 Wqkv + 256 Wo) —
//   coalesced 256B row reads + coalesced 128B row writes (the R6 version's
//   256B-4KB strided reads were ~16x line over-fetch).
// grid [1024,9216): x->bf16 elementwise | [9216,9228): bias pack.
__global__ void k_pack_all(const float* __restrict__ x,
                           const float* __restrict__ Wq, const float* __restrict__ Wk,
                           const float* __restrict__ Wv,
                           const float* __restrict__ bq, const float* __restrict__ bk,
                           const float* __restrict__ bv,
                           const float* __restrict__ Wo,
                           u16* __restrict__ xb, u16* __restrict__ Wt,
                           float* __restrict__ bqkv, u16* __restrict__ Wot) {
  __shared__ __align__(16) u16 tile[64][72];
  const int bid = blockIdx.x;
  const int t = threadIdx.x;
  if (bid < 1024) {
    const float* src;
    u16* dstp;
    int rstride, n_base, d0;
    if (bid < 768) {     // Wt[proj*1024+h*64+e][d] = Wp[h][d][e]
      const int proj = bid >> 8, h = (bid >> 4) & 15, dt = bid & 15;
      const float* Wp = (proj == 0) ? Wq : ((proj == 1) ? Wk : Wv);
      src = Wp + h * 65536 + (dt * 64) * 64;
      rstride = 64;
      n_base = proj * 1024 + h * 64;
      d0 = dt * 64;
      dstp = Wt;
    } else {             // Wot[n][d] = Wo[d][n]
      const int tb = bid - 768, nt = tb >> 4, dt = tb & 15;
      src = Wo + (size_t)(dt * 64) * 1024 + nt * 64;
      rstride = 1024;
      n_base = nt * 64;
      d0 = dt * 64;
      dstp = Wot;
    }
    {  // read 64 rows x 64 cols, coalesced; convert; stage in LDS
      const int row = t >> 2, c0 = (t & 3) * 16;
      const float* s = src + row * rstride + c0;
#pragma unroll
      for (int j = 0; j < 4; ++j) {
        const float4 v = *(const float4*)(s + j * 4);
        ushort4 o;
        o.x = f2bf(v.x); o.y = f2bf(v.y); o.z = f2bf(v.z); o.w = f2bf(v.w);
        *(ushort4*)&tile[row][c0 + j * 4] = o;
      }
    }
    __syncthreads();
    {  // write transposed, coalesced (4 threads x 32B per output row)
      const int e = t >> 2, c0 = (t & 3) * 16;
      u16 buf[16];
#pragma unroll
      for (int i = 0; i < 16; ++i) buf[i] = tile[c0 + i][e];
      u16* d = dstp + (size_t)(n_base + e) * 1024 + d0 + c0;
      *(u16x8*)d = *(const u16x8*)&buf[0];
      *(u16x8*)(d + 8) = *(const u16x8*)&buf[8];
    }
  } else if (bid < 9216) {
    const int i = ((bid - 1024) * 256 + t) * 4;
    const float4 v = *(const float4*)(x + i);
    ushort4 o;
    o.x = f2bf(v.x); o.y = f2bf(v.y); o.z = f2bf(v.z); o.w = f2bf(v.w);
    *(ushort4*)(xb + i) = o;
  } else {
    const int n = (bid - 9216) * 256 + t;
    const int proj = n >> 10, rem = n & 1023, h = rem >> 6, e = rem & 63;
    const float* bp = (proj == 0) ? bq : ((proj == 1) ? bk : bv);
    bqkv[n] = bp[h * 64 + e];
  }
}

// ----------------------------------------------------------------- GEMM ----
// (m97 structure). MODE 0: bf16 out, Q cols scaled by 0.125*log2e (exp2 domain).
template <int MODE>
__global__ __launch_bounds__(256)
void k_gemm(const u16* __restrict__ A, const u16* __restrict__ Bt,
            const float* __restrict__ bias, void* __restrict__ Cout, int ldc) {
  __shared__ __align__(16) u16 Alds[128 * 32];
  __shared__ __align__(16) u16 Blds[128 * 32];
  const int t = threadIdx.x;
  const int lane = t & 63;
  const int w = t >> 6;
  const int l15 = lane & 15;
  const int quad = lane >> 4;
  const int wm = w >> 1, wn = w & 1;
  const int m0 = blockIdx.y << 7;
  const int n0 = blockIdx.x << 7;

  const u16* ga0 = A + (size_t)(m0 + (t >> 2)) * 1024 + (t & 3) * 8;
  const u16* ga1 = ga0 + (size_t)64 * 1024;
  const u16* gb0 = Bt + (size_t)(n0 + (t >> 2)) * 1024 + (t & 3) * 8;
  const u16* gb1 = gb0 + (size_t)64 * 1024;
  u16* const lA0 = Alds + w * 512;
  u16* const lA1 = Alds + w * 512 + 2048;
  u16* const lB0 = Blds + w * 512;
  u16* const lB1 = Blds + w * 512 + 2048;

  f32x4 acc[4][4];
#pragma unroll
  for (int mi = 0; mi < 4; ++mi)
#pragma unroll
    for (int ni = 0; ni < 4; ++ni) acc[mi][ni] = (f32x4){0.f, 0.f, 0.f, 0.f};

  for (int k0 = 0; k0 < 1024; k0 += 32) {
    __syncthreads();
    async16(ga0, lA0); async16(ga1, lA1);
    async16(gb0, lB0); async16(gb1, lB1);
    ga0 += 32; ga1 += 32; gb0 += 32; gb1 += 32;
    __syncthreads();
    bf16x8 af[4], bfr[4];
#pragma unroll
    for (int i = 0; i < 4; ++i) {
      af[i]  = *(const bf16x8*)(Alds + (wm * 64 + i * 16 + l15) * 32 + quad * 8);
      bfr[i] = *(const bf16x8*)(Blds + (wn * 64 + i * 16 + l15) * 32 + quad * 8);
    }
#pragma unroll
    for (int mi = 0; mi < 4; ++mi)
#pragma unroll
      for (int ni = 0; ni < 4; ++ni)
        acc[mi][ni] = __builtin_amdgcn_mfma_f32_16x16x32_bf16(af[mi], bfr[ni], acc[mi][ni], 0, 0, 0);
  }

  const int row0 = m0 + wm * 64;
  const int col0 = n0 + wn * 64;
  // Q prescale: 1/sqrt(64) * log2(e) so attention can use bare v_exp_f32 (exp2)
  const float qscale = (MODE == 0 && col0 < 1024) ? 0.125f * 1.4426950408889634f : 1.0f;
#pragma unroll
  for (int mi = 0; mi < 4; ++mi) {
#pragma unroll
    for (int ni = 0; ni < 4; ++ni) {
      const int col = col0 + ni * 16 + l15;
      const float bb = bias[col];
#pragma unroll
      for (int r = 0; r < 4; ++r) {
        const int row = row0 + mi * 16 + quad * 4 + r;
        const float v = (acc[mi][ni][r] + bb) * qscale;
        if (MODE == 0) ((u16*)Cout)[(size_t)row * ldc + col] = f2bf(v);
        else           ((float*)Cout)[(size_t)row * ldc + col] = v;
      }
    }
  }
}

// ------------------------------------------------- V global transpose ----
// Vtg[bh][e][s] = QKV[b*2048+s][2048 + h*64 + e]
__global__ __launch_bounds__(256)
void k_vt(const u16* __restrict__ qkv, u16* __restrict__ vtg) {
  __shared__ u16 tile[64][72];
  const int t = threadIdx.x;
  const int bh = blockIdx.y, b = bh >> 4, h = bh & 15;
  const int s0 = blockIdx.x << 6;
  {
    const int row = t >> 2, col0 = (t & 3) * 16;
    const u16* src = qkv + (size_t)(b * 2048 + s0 + row) * 3072 + 2048 + h * 64 + col0;
    const u16x8 v0 = *(const u16x8*)src;
    const u16x8 v1 = *(const u16x8*)(src + 8);
    *(u16x8*)&tile[row][col0] = v0;
    *(u16x8*)&tile[row][col0 + 8] = v1;
  }
  __syncthreads();
  {
    const int e = t >> 2, sc = (t & 3) * 16;
    u16 buf[16];
#pragma unroll
    for (int i = 0; i < 16; ++i) buf[i] = tile[sc + i][e];
    u16* dst = vtg + ((size_t)bh * 64 + e) * 2048 + s0 + sc;
    *(u16x8*)dst = *(const u16x8*)&buf[0];
    *(u16x8*)(dst + 8) = *(const u16x8*)&buf[8];
  }
}

// ------------------------------------------------------------- attention ----
// Block = (bh, 128 q rows), 4 waves x 32 q each (2 groups of 16).
// Grid (64 bh, 16 qtile): linear id = y*64+x -> XCD = bh&7, so all 16
// q-tiles of one bh share an XCD and its K/V (512 KB) stays L2-resident
// (R6's (16,64) grid spread them over all 8 XCDs -> FETCH 139 MB vs 48
// unique).
// Per K-tile (128 keys): S^T = K.Q^T (A = K-frags from LDS under permutation
// pi; B = Q-frags in regs). Scores in log2-domain -> p = exp2(s). Packed
// exp2 register pairs ARE the PV A-fragment for key-chunk ks.
// l is computed BY MFMA (B = all-ones frag): lacc[g][r] = sum_key P[q][key]
// lands in the same row layout as o -> no VALU lsum adds, no shuffles.
// Register note: plain launch_bounds(256) — a min-waves clause clamped the
// unified VGPR file and spilled (R4: WRITE_SIZE 16->171 MB).
__global__ __launch_bounds__(256)
void k_attn(const u16* __restrict__ qkv, const u16* __restrict__ vtg,
            u16* __restrict__ mh) {
  __shared__ __align__(16) u16 smem[16384];
  u16* const Klds = smem;          // 128 keys x 8 chunks(8 u16), chunk-swizzled
  u16* const Vlds = smem + 8192;   // 64 e x 16 chunks, chunk-swizzled

  const int t = threadIdx.x;
  const int lane = t & 63;
  const int w = t >> 6;
  const int l15 = lane & 15;
  const int quad = lane >> 4;
  const int bh = blockIdx.x, b = bh >> 4, h = bh & 15;
  const int s0 = blockIdx.y << 7;   // 128 q rows per block

  // K staging base (r=0): lam0 = t>>3 in [0,32), key0 = pi(lam0) (bits 5,6 = 0)
  const int lam0 = t >> 3;
  const int key0 = (lam0 & 3) | (((lam0 >> 2) & 3) << 3) | (((lam0 >> 4) & 1) << 2);
  const int ck = (t & 7) ^ (lam0 & 7);
  const u16* kbase = qkv + (size_t)(b * 2048 + key0) * 3072 + 1024 + h * 64 + ck * 8;
  // V staging base (r=0): e0 = t>>4 in [0,16), chunk = (t&15) ^ e0
  const int e0 = t >> 4;
  const int cv = (t & 15) ^ e0;
  const u16* vbase = vtg + ((size_t)bh * 64 + e0) * 2048 + cv * 8;
  u16* const KldsW = Klds + w * 512;
  u16* const VldsW = Vlds + w * 512;

  // Q frags (B-operand) direct from global: q = w*32 + g*16 + l15
  bf16x8 aq[2][2];
#pragma unroll
  for (int g = 0; g < 2; ++g)
#pragma unroll
    for (int ks2 = 0; ks2 < 2; ++ks2)
      aq[g][ks2] = *(const bf16x8*)(qkv +
          (size_t)(b * 2048 + s0 + w * 32 + g * 16 + l15) * 3072 +
          h * 64 + ks2 * 32 + quad * 8);

  // all-ones B-frag for the l-MFMA (bf16 1.0 = 0x3F80)
  const u32x4 onesu = (u32x4){0x3F803F80u, 0x3F803F80u, 0x3F803F80u, 0x3F803F80u};
  const bf16x8 ones = __builtin_bit_cast(bf16x8, onesu);

  f32x4 o[2][4];
  f32x4 lacc[2];
#pragma unroll
  for (int g = 0; g < 2; ++g) {
    lacc[g] = (f32x4){0.f, 0.f, 0.f, 0.f};
#pragma unroll
    for (int ne = 0; ne < 4; ++ne) o[g][ne] = (f32x4){0.f, 0.f, 0.f, 0.f};
  }

  for (int kt = 0; kt < 16; ++kt) {
    __syncthreads();  // prior tile reads done
#pragma unroll
    for (int r = 0; r < 4; ++r)
      async16(kbase + r * (32 * 3072), KldsW + r * 2048);
#pragma unroll
    for (int r = 0; r < 4; ++r)
      async16(vbase + r * (16 * 2048), VldsW + r * 2048);
    kbase += 128 * 3072;
    vbase += 128;
    __syncthreads();

#pragma unroll
    for (int ks = 0; ks < 4; ++ks) {
      u32x4 pf[2];  // per-g PV A-frag for key-chunk ks
#pragma unroll
      for (int h2 = 0; h2 < 2; ++h2) {
        const int kt8 = ks * 2 + h2;
        const int row = kt8 * 16 + l15;
        const bf16x8 kf0 = *(const bf16x8*)(Klds + row * 64 + ((quad) ^ (l15 & 7)) * 8);
        const bf16x8 kf1 = *(const bf16x8*)(Klds + row * 64 + ((4 + quad) ^ (l15 & 7)) * 8);
        f32x4 st[2];
#pragma unroll
        for (int g = 0; g < 2; ++g) {
          st[g] = __builtin_amdgcn_mfma_f32_16x16x32_bf16(kf0, aq[g][0], (f32x4){0.f,0.f,0.f,0.f}, 0, 0, 0);
          st[g] = __builtin_amdgcn_mfma_f32_16x16x32_bf16(kf1, aq[g][1], st[g], 0, 0, 0);
        }
#pragma unroll
        for (int g = 0; g < 2; ++g) {
          const float p0 = ex2(st[g][0]), p1 = ex2(st[g][1]);
          const float p2 = ex2(st[g][2]), p3 = ex2(st[g][3]);
          pf[g][h2 * 2 + 0] = pk2c(p0, p1);
          pf[g][h2 * 2 + 1] = pk2c(p2, p3);
        }
      }
#pragma unroll
      for (int ne = 0; ne < 4; ++ne) {
        const int e = ne * 16 + l15;
        const bf16x8 bv8 = *(const bf16x8*)(Vlds + e * 128 + (((ks * 4 + quad) ^ l15) & 15) * 8);
#pragma unroll
        for (int g = 0; g < 2; ++g)
          o[g][ne] = __builtin_amdgcn_mfma_f32_16x16x32_bf16(
              __builtin_bit_cast(bf16x8, pf[g]), bv8, o[g][ne], 0, 0, 0);
      }
#pragma unroll
      for (int g = 0; g < 2; ++g)
        lacc[g] = __builtin_amdgcn_mfma_f32_16x16x32_bf16(
            __builtin_bit_cast(bf16x8, pf[g]), ones, lacc[g], 0, 0, 0);
    }
  }

  // epilogue: O row = quad*4+r within group; lacc has the SAME row layout,
  // so inv is per-(g,r) with no cross-lane traffic.
#pragma unroll
  for (int g = 0; g < 2; ++g) {
#pragma unroll
    for (int r = 0; r < 4; ++r) {
      const float iv = 1.f / lacc[g][r];
      const int row = s0 + w * 32 + g * 16 + quad * 4 + r;
#pragma unroll
      for (int ne = 0; ne < 4; ++ne) {
        const int col = h * 64 + ne * 16 + l15;
        mh[(size_t)(b * 2048 + row) * 1024 + col] = f2bf(o[g][ne][r] * iv);
      }
    }
  }
}

// ---------------------------------------------------------------- launch ----
extern "C" void kernel_launch(void* const* d_in, const int* in_sizes, int n_in,
                              void* d_out, int out_size, void* d_ws, size_t ws_size,
                              hipStream_t stream) {
  (void)in_sizes; (void)n_in; (void)out_size; (void)ws_size;
  const float* x  = (const float*)d_in[0];
  const float* Wq = (const float*)d_in[1];
  const float* bq = (const float*)d_in[2];
  const float* Wk = (const float*)d_in[3];
  const float* bk = (const float*)d_in[4];
  const float* Wv = (const float*)d_in[5];
  const float* bv = (const float*)d_in[6];
  const float* Wo = (const float*)d_in[7];
  const float* bo = (const float*)d_in[8];

  char* ws = (char*)d_ws;
  u16*   Xb   = (u16*)  (ws + 0);          // 16777216 B (dead after gemm_qkv)
  u16*   Vtg  = (u16*)  (ws + 0);          // aliases Xb, written after
  u16*   Wt   = (u16*)  (ws + 16777216);   //  6291456
  float* bqkv = (float*)(ws + 23068672);   //    12288
  u16*   Wot  = (u16*)  (ws + 23080960);   //  2097152
  u16*   QKV  = (u16*)  (ws + 25178112);   // 50331648
  u16*   MH   = (u16*)  (ws + 75509760);   // 16777216  (total ~92.3 MB)
  float* out  = (float*)d_out;

  k_pack_all <<<9228, 256, 0, stream>>>(x, Wq, Wk, Wv, bq, bk, bv, Wo,
                                        Xb, Wt, bqkv, Wot);
  k_gemm<0>  <<<dim3(24, 64), 256, 0, stream>>>(Xb, Wt, bqkv, (void*)QKV, 3072);
  k_vt       <<<dim3(32, 64), 256, 0, stream>>>(QKV, Vtg);
  k_attn     <<<dim3(64, 16), 256, 0, stream>>>(QKV, Vtg, MH);
  k_gemm<1>  <<<dim3(8, 64), 256, 0, stream>>>(MH, Wot, bo, (void*)out, 1024);
}